// Round 16
// baseline (316.822 us; speedup 1.0000x reference)
//
#include <hip/hip_runtime.h>
#include <cstdint>
#include <cmath>

#define NEG_SLOPE 0.2f
#define BSH 6                 // 64-node granularity for chunk_hist LDS hist
#define CSH 9                 // 512 nodes per coarse bucket
#define CBN 512               // 1 << CSH
#define RATIO 8               // CBN / 64
#define PCHUNK 8192           // edges per partition/hist chunk

__device__ __forceinline__ float leaky(float v) { return v > 0.f ? v : NEG_SLOPE * v; }
__device__ __forceinline__ float uf(unsigned u) { return __uint_as_float(u); }

// f32 -> bf16 round-to-nearest-even (finite inputs)
__device__ __forceinline__ unsigned short f2bf(float f) {
    unsigned u = __float_as_uint(f);
    unsigned r = ((u >> 16) & 1u) + 0x7fffu;
    return (unsigned short)((u + r) >> 16);
}
__device__ __forceinline__ float bflo(unsigned q) { return __uint_as_float(q << 16); }
__device__ __forceinline__ float bfhi(unsigned q) { return __uint_as_float(q & 0xffff0000u); }

// ---------------------------------------------------------------------------
// Skinny GEMM + attention-coefficient dots + per-block As-max (NO atomics):
//   H[n,:] = bf16(X[n,:] @ W) ;  As/Ad from full-precision acc;
//   bmax[blockIdx] = max As in block  (tiny reduce kernel folds to gmax).
// ---------------------------------------------------------------------------
template <int FIN, int FOUT, int CPR, int LCPR>
__global__ __launch_bounds__(256, 4) void gemm_rows(
    const float* __restrict__ X, const float* __restrict__ W,
    const float* __restrict__ a_src, const float* __restrict__ a_dst,
    unsigned short* __restrict__ H, float* __restrict__ As, float* __restrict__ Ad,
    float* __restrict__ bmax, int N)
{
    constexpr int ROWS = 256 / CPR;
    constexpr int XST = FIN + 4;              // padded row stride (floats)
    static_assert((1 << LCPR) == CPR && CPR * 4 == FOUT, "geometry");

    __shared__ float Ws[FIN * FOUT];
    __shared__ float Xs[ROWS * XST];
    __shared__ float wmax[4];

    const int tid = threadIdx.x;
    const int base = blockIdx.x * ROWS;

    for (int i = tid; i < FIN * FOUT / 4; i += 256)
        reinterpret_cast<float4*>(Ws)[i] = reinterpret_cast<const float4*>(W)[i];

    for (int i = tid; i < ROWS * FIN / 4; i += 256) {
        int row = i / (FIN / 4);
        int k4 = (i - row * (FIN / 4)) * 4;
        float4 v = make_float4(0.f, 0.f, 0.f, 0.f);
        if (base + row < N)
            v = *reinterpret_cast<const float4*>(&X[(size_t)(base + row) * FIN + k4]);
        *reinterpret_cast<float4*>(&Xs[row * XST + k4]) = v;
    }
    __syncthreads();

    const int colg = tid & (CPR - 1);
    const int row = tid >> LCPR;
    const int c0 = colg * 4;

    float4 acc = make_float4(0.f, 0.f, 0.f, 0.f);

#pragma unroll 2
    for (int k = 0; k < FIN; k += 4) {
        float4 xv = *reinterpret_cast<const float4*>(&Xs[row * XST + k]);
        float4 w0 = *reinterpret_cast<const float4*>(&Ws[(k + 0) * FOUT + c0]);
        float4 w1 = *reinterpret_cast<const float4*>(&Ws[(k + 1) * FOUT + c0]);
        float4 w2 = *reinterpret_cast<const float4*>(&Ws[(k + 2) * FOUT + c0]);
        float4 w3 = *reinterpret_cast<const float4*>(&Ws[(k + 3) * FOUT + c0]);
        acc.x = fmaf(xv.w, w3.x, fmaf(xv.z, w2.x, fmaf(xv.y, w1.x, fmaf(xv.x, w0.x, acc.x))));
        acc.y = fmaf(xv.w, w3.y, fmaf(xv.z, w2.y, fmaf(xv.y, w1.y, fmaf(xv.x, w0.y, acc.y))));
        acc.z = fmaf(xv.w, w3.z, fmaf(xv.z, w2.z, fmaf(xv.y, w1.z, fmaf(xv.x, w0.z, acc.z))));
        acc.w = fmaf(xv.w, w3.w, fmaf(xv.z, w2.w, fmaf(xv.y, w1.w, fmaf(xv.x, w0.w, acc.w))));
    }

    const int grow = base + row;
    if (grow < N) {
        ushort4 hv;
        hv.x = f2bf(acc.x); hv.y = f2bf(acc.y);
        hv.z = f2bf(acc.z); hv.w = f2bf(acc.w);
        *reinterpret_cast<ushort4*>(&H[(size_t)grow * FOUT + c0]) = hv;
    }

    float4 asv = *reinterpret_cast<const float4*>(&a_src[c0]);
    float4 adv = *reinterpret_cast<const float4*>(&a_dst[c0]);
    float ps = acc.x * asv.x + acc.y * asv.y + acc.z * asv.z + acc.w * asv.w;
    float pd = acc.x * adv.x + acc.y * adv.y + acc.z * adv.z + acc.w * adv.w;
#pragma unroll
    for (int ofs = 1; ofs < CPR; ofs <<= 1) {
        ps += __shfl_xor(ps, ofs);
        pd += __shfl_xor(pd, ofs);
    }
    if (colg == 0 && grow < N) { As[grow] = ps; Ad[grow] = pd; }

    // block max of As -> bmax[blockIdx] (no atomics)
    float pm = (grow < N) ? ps : -3.0e38f;
#pragma unroll
    for (int ofs = 1; ofs < 64; ofs <<= 1) pm = fmaxf(pm, __shfl_xor(pm, ofs));
    if ((tid & 63) == 0) wmax[tid >> 6] = pm;
    __syncthreads();
    if (tid == 0)
        bmax[blockIdx.x] = fmaxf(fmaxf(wmax[0], wmax[1]), fmaxf(wmax[2], wmax[3]));
}

// single block: gmax = max(bmax[0..nb))
__global__ __launch_bounds__(256) void reduce_max_kernel(
    const float* __restrict__ bmax, int nb, float* __restrict__ gmax)
{
    __shared__ float sd[256];
    const int t = threadIdx.x;
    float m = -3.0e38f;
    for (int i = t; i < nb; i += 256) m = fmaxf(m, bmax[i]);
    sd[t] = m; __syncthreads();
    for (int ofs = 128; ofs; ofs >>= 1) {
        if (t < ofs) sd[t] = fmaxf(sd[t], sd[t + ofs]);
        __syncthreads();
    }
    if (t == 0) *gmax = sd[0];
}

// single block: gmax = max(bmax) ; also w2s = W2@a2s, w2d = W2@a2d (t<64).
__global__ __launch_bounds__(256) void rmax_w2prep(
    const float* __restrict__ bmax, int nb, float* __restrict__ gmax,
    const float* __restrict__ W2, const float* __restrict__ a2s,
    const float* __restrict__ a2d, float* __restrict__ w2s, float* __restrict__ w2d)
{
    __shared__ float sd[256];
    const int t = threadIdx.x;
    float m = -3.0e38f;
    for (int i = t; i < nb; i += 256) m = fmaxf(m, bmax[i]);
    sd[t] = m; __syncthreads();
    for (int ofs = 128; ofs; ofs >>= 1) {
        if (t < ofs) sd[t] = fmaxf(sd[t], sd[t + ofs]);
        __syncthreads();
    }
    if (t == 0) *gmax = sd[0];
    if (t < 64) {
        int i = t & 31;
        const float* a = (t < 32) ? a2s : a2d;
        float s = 0.f;
        for (int j = 0; j < 64; ++j) s = fmaf(W2[i * 64 + j], a[j], s);
        if (t < 32) w2s[i] = s; else w2d[i] = s;
    }
}

// ---------------------------------------------------------------------------
// CSR build (r13 form): 6 kernels, zero global atomics, no per-call memset.
// ---------------------------------------------------------------------------
__global__ __launch_bounds__(256) void chunk_hist(
    const int* __restrict__ dst, int* __restrict__ pcT,
    int E, int NB, int NCC, int NCH)
{
    __shared__ int hc[2048];
    const int t = threadIdx.x;
    for (int i = t; i < 2048; i += 256) hc[i] = 0;
    __syncthreads();
    const int base = blockIdx.x * PCHUNK;
    const int end = (base + PCHUNK < E) ? base + PCHUNK : E;
    for (int e = base + t; e < end; e += 256)
        atomicAdd(&hc[dst[e] >> BSH], 1);
    __syncthreads();
    if (t < NCC) {
        int f0 = t * RATIO;
        int s = 0;
#pragma unroll
        for (int j = 0; j < RATIO; ++j) {
            int fb = f0 + j;
            if (fb < NB) s += hc[fb];
        }
        pcT[(size_t)t * NCH + blockIdx.x] = s;
    }
}

__global__ __launch_bounds__(256) void coarse_total(
    const int* __restrict__ pcT, int* __restrict__ totals, int NCH)
{
    __shared__ int sd[256];
    const int t = threadIdx.x;
    int s = 0;
    for (int i = t; i < NCH; i += 256)
        s += pcT[(size_t)blockIdx.x * NCH + i];
    sd[t] = s; __syncthreads();
    for (int ofs = 128; ofs; ofs >>= 1) {
        if (t < ofs) sd[t] += sd[t + ofs];
        __syncthreads();
    }
    if (t == 0) totals[blockIdx.x] = sd[0];
}

__global__ __launch_bounds__(256) void boffc_scan(
    const int* __restrict__ totals, int* __restrict__ boffC, int NCC)
{
    __shared__ int sd[256];
    const int t = threadIdx.x;
    int v = (t < NCC) ? totals[t] : 0;
    sd[t] = v; __syncthreads();
    for (int ofs = 1; ofs < 256; ofs <<= 1) {
        int tmp = (t >= ofs) ? sd[t - ofs] : 0;
        __syncthreads();
        sd[t] += tmp;
        __syncthreads();
    }
    if (t < NCC) boffC[t] = sd[t] - v;
    if (t == 255) boffC[NCC] = sd[255];   // == E
}

__global__ __launch_bounds__(256) void coarse_scan(
    const int* __restrict__ pcT, const int* __restrict__ boffC,
    int* __restrict__ co, int NCH)
{
    __shared__ int sd[256];
    const int c = blockIdx.x;
    const int t = threadIdx.x;
    const int base = boffC[c];
    int carry = 0;
    for (int start = 0; start < NCH; start += 256) {
        int idx = start + t;
        int v = (idx < NCH) ? pcT[(size_t)c * NCH + idx] : 0;
        sd[t] = v; __syncthreads();
        for (int ofs = 1; ofs < 256; ofs <<= 1) {
            int tmp = (t >= ofs) ? sd[t - ofs] : 0;
            __syncthreads();
            sd[t] += tmp;
            __syncthreads();
        }
        int incl = sd[t];
        int total = sd[255];
        if (idx < NCH) co[(size_t)idx * 256 + c] = base + carry + incl - v;
        carry += total;
        __syncthreads();
    }
}

__global__ __launch_bounds__(256) void coarse_partition(
    const int* __restrict__ src, const int* __restrict__ dst,
    const int* __restrict__ co, int* __restrict__ csrA, int E, int NCC)
{
    __shared__ int lcur[256], gpos[256];
    const int t = threadIdx.x;
    lcur[t] = 0;
    if (t < NCC) gpos[t] = co[(size_t)blockIdx.x * 256 + t];
    __syncthreads();
    const int base = blockIdx.x * PCHUNK;
    int bb[32], pp[32];
#pragma unroll
    for (int i = 0; i < 32; ++i) {
        int e = base + i * 256 + t;
        bb[i] = -1;
        if (e < E) {
            int sv = src[e], dv = dst[e];
            bb[i] = dv >> CSH;
            pp[i] = (sv << CSH) | (dv & (CBN - 1));
        }
    }
#pragma unroll
    for (int i = 0; i < 32; ++i) {
        if (bb[i] >= 0) {
            int b = bb[i];
            csrA[gpos[b] + atomicAdd(&lcur[b], 1)] = pp[i];
        }
    }
}

__global__ __launch_bounds__(256) void node_sort(
    const int* __restrict__ csrA, const int* __restrict__ boffC,
    int* __restrict__ off, int* __restrict__ csr, int N, int NCC, int E)
{
    __shared__ int cnt[CBN];
    __shared__ int pref[CBN];
    __shared__ int sd[256];
    const int c = blockIdx.x;
    const int t = threadIdx.x;
    const int p0 = boffC[c];
    const int p1 = boffC[c + 1];
    const int n0 = c << CSH;

    for (int i = t; i < CBN; i += 256) cnt[i] = 0;
    __syncthreads();
    for (int i = p0 + t; i < p1; i += 256)
        atomicAdd(&cnt[csrA[i] & (CBN - 1)], 1);
    __syncthreads();
    int a0 = cnt[2 * t], a1 = cnt[2 * t + 1];
    int pairsum = a0 + a1;
    sd[t] = pairsum; __syncthreads();
    for (int ofs = 1; ofs < 256; ofs <<= 1) {
        int tmp = (t >= ofs) ? sd[t - ofs] : 0;
        __syncthreads();
        sd[t] += tmp;
        __syncthreads();
    }
    int run = sd[t] - pairsum;
    pref[2 * t] = run;
    pref[2 * t + 1] = run + a0;
    int n = n0 + 2 * t;
    if (n < N) off[n] = p0 + run;
    if (n + 1 < N) off[n + 1] = p0 + run + a0;
    if (c == NCC - 1 && t == 0) off[N] = E;
    __syncthreads();
    for (int i = t; i < CBN; i += 256) cnt[i] = 0;   // reuse as cursors
    __syncthreads();
    for (int i = p0 + t; i < p1; i += 256) {
        int v = csrA[i];
        int ln = v & (CBN - 1);
        int p = atomicAdd(&cnt[ln], 1);
        csr[p0 + pref[ln] + p] = v >> CSH;
    }
}

// ---------------------------------------------------------------------------
// Layer-1 aggregation + fused layer-2 alpha dots:
//   h1a = bf16(relu(agg/den + b1))  [gather table for agg2]
//   as2/ad2 from the exact f32 values (pre-rounding) via w2s/w2d
//   per-wave as2 maxima -> bmaxw (dead waves write -3e38).
// ---------------------------------------------------------------------------
__global__ __launch_bounds__(256) void gat_agg1(
    const int* __restrict__ csr, const int* __restrict__ off,
    const float* __restrict__ As, const float* __restrict__ Ad,
    const unsigned short* __restrict__ Hb, const float* __restrict__ bias,
    const float* __restrict__ gmax, const float* __restrict__ w2s,
    const float* __restrict__ w2d, unsigned short* __restrict__ Out,
    float* __restrict__ As2, float* __restrict__ Ad2,
    float* __restrict__ bmaxw, int N)
{
    constexpr int LPR = 8;            // lanes per row (4 bf16 per lane)
    constexpr int EPI = 8;            // edges in flight
    constexpr unsigned RB = 64;       // row bytes

    __shared__ uint2 pr[4][64];
    const int wave = threadIdx.x >> 6;
    const int lane = threadIdx.x & 63;
    const int n = blockIdx.x * 4 + wave;
    if (n >= N) {
        if (lane == 0) bmaxw[blockIdx.x * 4 + wave] = -3.0e38f;
        return;
    }

    const int o0 = off[n];
    const int deg = off[n + 1] - o0;
    const float adn = Ad[n];
    const float eself = leaky(As[n] + adn);
    const float m = leaky(*gmax + adn);

    uint2* myp = pr[wave];
    const char* Hc = (const char*)Hb;
    const int subg = lane / LPR;
    const unsigned f8 = (unsigned)(lane & (LPR - 1)) * 8u;

    float4 acc = make_float4(0.f, 0.f, 0.f, 0.f);
    float denp = 0.f;

    for (int c = 0; c < deg; c += 64) {
        int i = c + lane;
        float w = 0.f; unsigned sb = 0;
        if (i < deg) {
            int s = csr[o0 + i];
            w = __expf(leaky(As[s] + adn) - m);
            sb = (unsigned)s * RB;
            denp += w;
        }
        myp[lane] = make_uint2(sb, __float_as_uint(w));
        int lim = (deg - c < 64) ? deg - c : 64;
        int j = subg;
        for (; j + 3 * EPI < lim; j += 4 * EPI) {
            uint2 p0 = myp[j], p1 = myp[j + EPI], p2 = myp[j + 2 * EPI], p3 = myp[j + 3 * EPI];
            uint2 q0 = *(const uint2*)(Hc + p0.x + f8);
            uint2 q1 = *(const uint2*)(Hc + p1.x + f8);
            uint2 q2 = *(const uint2*)(Hc + p2.x + f8);
            uint2 q3 = *(const uint2*)(Hc + p3.x + f8);
            float w0 = uf(p0.y), w1 = uf(p1.y), w2 = uf(p2.y), w3 = uf(p3.y);
            acc.x = fmaf(w0, bflo(q0.x), acc.x); acc.y = fmaf(w0, bfhi(q0.x), acc.y);
            acc.z = fmaf(w0, bflo(q0.y), acc.z); acc.w = fmaf(w0, bfhi(q0.y), acc.w);
            acc.x = fmaf(w1, bflo(q1.x), acc.x); acc.y = fmaf(w1, bfhi(q1.x), acc.y);
            acc.z = fmaf(w1, bflo(q1.y), acc.z); acc.w = fmaf(w1, bfhi(q1.y), acc.w);
            acc.x = fmaf(w2, bflo(q2.x), acc.x); acc.y = fmaf(w2, bfhi(q2.x), acc.y);
            acc.z = fmaf(w2, bflo(q2.y), acc.z); acc.w = fmaf(w2, bfhi(q2.y), acc.w);
            acc.x = fmaf(w3, bflo(q3.x), acc.x); acc.y = fmaf(w3, bfhi(q3.x), acc.y);
            acc.z = fmaf(w3, bflo(q3.y), acc.z); acc.w = fmaf(w3, bfhi(q3.y), acc.w);
        }
        for (; j < lim; j += EPI) {
            uint2 p = myp[j];
            uint2 q = *(const uint2*)(Hc + p.x + f8);
            float w0 = uf(p.y);
            acc.x = fmaf(w0, bflo(q.x), acc.x); acc.y = fmaf(w0, bfhi(q.x), acc.y);
            acc.z = fmaf(w0, bflo(q.y), acc.z); acc.w = fmaf(w0, bfhi(q.y), acc.w);
        }
    }

#pragma unroll
    for (int ofs = 32; ofs >= LPR; ofs >>= 1) {
        acc.x += __shfl_xor(acc.x, ofs);
        acc.y += __shfl_xor(acc.y, ofs);
        acc.z += __shfl_xor(acc.z, ofs);
        acc.w += __shfl_xor(acc.w, ofs);
    }
#pragma unroll
    for (int ofs = 1; ofs < 64; ofs <<= 1) denp += __shfl_xor(denp, ofs);

    float wsf = __expf(eself - m);
    uint2 qs = *(const uint2*)(Hc + (size_t)n * RB + f8);
    acc.x = fmaf(wsf, bflo(qs.x), acc.x); acc.y = fmaf(wsf, bfhi(qs.x), acc.y);
    acc.z = fmaf(wsf, bflo(qs.y), acc.z); acc.w = fmaf(wsf, bfhi(qs.y), acc.w);
    float den = denp + wsf;

    // every lane now holds the reduced acc for its 4-feature slot
    const int fi = (lane & (LPR - 1)) * 4;
    float4 bv = *reinterpret_cast<const float4*>(&bias[fi]);
    float vx = fmaxf(acc.x / den + bv.x, 0.f);
    float vy = fmaxf(acc.y / den + bv.y, 0.f);
    float vz = fmaxf(acc.z / den + bv.z, 0.f);
    float vw = fmaxf(acc.w / den + bv.w, 0.f);

    if (subg == 0) {
        ushort4 hv;
        hv.x = f2bf(vx); hv.y = f2bf(vy); hv.z = f2bf(vz); hv.w = f2bf(vw);
        *reinterpret_cast<ushort4*>(&Out[(size_t)n * 32 + fi]) = hv;
    }

    // fused alpha2 from exact f32 values (bit-identical to separate f32 pass)
    float ps = vx * w2s[fi] + vy * w2s[fi + 1] + vz * w2s[fi + 2] + vw * w2s[fi + 3];
    float pd = vx * w2d[fi] + vy * w2d[fi + 1] + vz * w2d[fi + 2] + vw * w2d[fi + 3];
#pragma unroll
    for (int ofs = 1; ofs < LPR; ofs <<= 1) {
        ps += __shfl_xor(ps, ofs);
        pd += __shfl_xor(pd, ofs);
    }
    if (lane == 0) {
        As2[n] = ps; Ad2[n] = pd;
        bmaxw[blockIdx.x * 4 + wave] = ps;
    }
}

// ---------------------------------------------------------------------------
// Layer-2 aggregation, fused @W2 (W2 read direct from global; L1-hot):
// gathers 64B bf16 h1a rows, agg32 = sum(alpha*h1a[s]) + self,
// out = agg32@W2/den + b2. No barriers.
// ---------------------------------------------------------------------------
__global__ __launch_bounds__(256) void gat_agg2(
    const int* __restrict__ csr, const int* __restrict__ off,
    const float* __restrict__ As, const float* __restrict__ Ad,
    const unsigned short* __restrict__ Hb, const float* __restrict__ W2,
    const float* __restrict__ b2, const float* __restrict__ gmax,
    float* __restrict__ Out, int N)
{
    constexpr int LPR = 8;
    constexpr int EPI = 8;
    constexpr unsigned RB = 64;

    __shared__ uint2 pr[4][64];
    __shared__ float aggv[4][32];

    const int tid = threadIdx.x;
    const int wave = tid >> 6;
    const int lane = tid & 63;
    const int n = blockIdx.x * 4 + wave;
    if (n >= N) return;

    const int o0 = off[n];
    const int deg = off[n + 1] - o0;
    const float adn = Ad[n];
    const float eself = leaky(As[n] + adn);
    const float m = leaky(*gmax + adn);

    uint2* myp = pr[wave];
    const char* Hc = (const char*)Hb;
    const int subg = lane / LPR;
    const unsigned f8 = (unsigned)(lane & (LPR - 1)) * 8u;

    float4 acc = make_float4(0.f, 0.f, 0.f, 0.f);
    float denp = 0.f;

    for (int c = 0; c < deg; c += 64) {
        int i = c + lane;
        float w = 0.f; unsigned sb = 0;
        if (i < deg) {
            int s = csr[o0 + i];
            w = __expf(leaky(As[s] + adn) - m);
            sb = (unsigned)s * RB;
            denp += w;
        }
        myp[lane] = make_uint2(sb, __float_as_uint(w));
        int lim = (deg - c < 64) ? deg - c : 64;
        int j = subg;
        for (; j + 3 * EPI < lim; j += 4 * EPI) {
            uint2 p0 = myp[j], p1 = myp[j + EPI], p2 = myp[j + 2 * EPI], p3 = myp[j + 3 * EPI];
            uint2 q0 = *(const uint2*)(Hc + p0.x + f8);
            uint2 q1 = *(const uint2*)(Hc + p1.x + f8);
            uint2 q2 = *(const uint2*)(Hc + p2.x + f8);
            uint2 q3 = *(const uint2*)(Hc + p3.x + f8);
            float w0 = uf(p0.y), w1 = uf(p1.y), w2 = uf(p2.y), w3 = uf(p3.y);
            acc.x = fmaf(w0, bflo(q0.x), acc.x); acc.y = fmaf(w0, bfhi(q0.x), acc.y);
            acc.z = fmaf(w0, bflo(q0.y), acc.z); acc.w = fmaf(w0, bfhi(q0.y), acc.w);
            acc.x = fmaf(w1, bflo(q1.x), acc.x); acc.y = fmaf(w1, bfhi(q1.x), acc.y);
            acc.z = fmaf(w1, bflo(q1.y), acc.z); acc.w = fmaf(w1, bfhi(q1.y), acc.w);
            acc.x = fmaf(w2, bflo(q2.x), acc.x); acc.y = fmaf(w2, bfhi(q2.x), acc.y);
            acc.z = fmaf(w2, bflo(q2.y), acc.z); acc.w = fmaf(w2, bfhi(q2.y), acc.w);
            acc.x = fmaf(w3, bflo(q3.x), acc.x); acc.y = fmaf(w3, bfhi(q3.x), acc.y);
            acc.z = fmaf(w3, bflo(q3.y), acc.z); acc.w = fmaf(w3, bfhi(q3.y), acc.w);
        }
        for (; j < lim; j += EPI) {
            uint2 p = myp[j];
            uint2 q = *(const uint2*)(Hc + p.x + f8);
            float w0 = uf(p.y);
            acc.x = fmaf(w0, bflo(q.x), acc.x); acc.y = fmaf(w0, bfhi(q.x), acc.y);
            acc.z = fmaf(w0, bflo(q.y), acc.z); acc.w = fmaf(w0, bfhi(q.y), acc.w);
        }
    }

#pragma unroll
    for (int ofs = 32; ofs >= LPR; ofs >>= 1) {
        acc.x += __shfl_xor(acc.x, ofs);
        acc.y += __shfl_xor(acc.y, ofs);
        acc.z += __shfl_xor(acc.z, ofs);
        acc.w += __shfl_xor(acc.w, ofs);
    }
#pragma unroll
    for (int ofs = 1; ofs < 64; ofs <<= 1) denp += __shfl_xor(denp, ofs);

    float wsf = __expf(eself - m);
    uint2 qs = *(const uint2*)(Hc + (size_t)n * RB + f8);
    acc.x = fmaf(wsf, bflo(qs.x), acc.x); acc.y = fmaf(wsf, bfhi(qs.x), acc.y);
    acc.z = fmaf(wsf, bflo(qs.y), acc.z); acc.w = fmaf(wsf, bfhi(qs.y), acc.w);
    float den = denp + wsf;

    if (subg == 0)
        *reinterpret_cast<float4*>(&aggv[wave][(lane & (LPR - 1)) * 4]) = acc;
    // same-wave LDS write->read is ordered; compiler inserts lgkmcnt wait

    float s = 0.f;
#pragma unroll
    for (int k = 0; k < 32; ++k)
        s = fmaf(aggv[wave][k], W2[k * 64 + lane], s);
    Out[(size_t)n * 64 + lane] = s / den + b2[lane];
}

// ---------------------------------------------------------------------------
extern "C" void kernel_launch(void* const* d_in, const int* in_sizes, int n_in,
                              void* d_out, int out_size, void* d_ws, size_t ws_size,
                              hipStream_t stream)
{
    const float* x   = (const float*)d_in[0];
    const int*   ei  = (const int*)d_in[1];   // [2, E] int32
    const float* W1  = (const float*)d_in[2];
    const float* a1s = (const float*)d_in[3];
    const float* a1d = (const float*)d_in[4];
    const float* b1  = (const float*)d_in[5];
    const float* W2  = (const float*)d_in[6];
    const float* a2s = (const float*)d_in[7];
    const float* a2d = (const float*)d_in[8];
    const float* b2  = (const float*)d_in[9];

    const int N = in_sizes[0] / 128;
    const int E = in_sizes[1] / 2;
    const int NB = (N + 63) >> BSH;                 // 64-node fine granularity
    const int NCC = (N + CBN - 1) >> CSH;           // coarse buckets (<=256)
    const int NCH = (E + PCHUNK - 1) / PCHUNK;
    const int* src = ei;
    const int* dst = ei + E;
    float* out = (float*)d_out;

    const int g1 = (N + 31) / 32;   // layer-1 gemm grid
    const int gn = (N + 3) / 4;     // aggregation grid

    // ---- workspace layout ----
    float* ws = (float*)d_ws;
    size_t o = 0;
    unsigned short* h1b = (unsigned short*)(ws + o); o += (size_t)N * 16;  // N*32 bf16
    unsigned short* h1a = (unsigned short*)(ws + o); o += (size_t)N * 16;  // N*32 bf16
    float* as1 = ws + o; o += N;
    float* ad1 = ws + o; o += N;
    float* as2 = ws + o; o += N;
    float* ad2 = ws + o; o += N;
    float* bmax = ws + o; o += (size_t)g1;
    float* bmaxw = ws + o; o += (size_t)gn * 4;
    float* gmax1 = ws + o; o += 1;
    float* gmax2 = ws + o; o += 1;
    float* w2s = ws + o; o += 32;
    float* w2d = ws + o; o += 32;
    int* ip = (int*)(ws + o);
    size_t io = 0;
    int* pcT    = ip + io; io += (size_t)NCC * NCH;
    int* totals = ip + io; io += NCC;
    int* boffC  = ip + io; io += (NCC + 1);
    int* co     = ip + io; io += (size_t)NCH * 256;
    int* off    = ip + io; io += (N + 1);
    int* csrA   = ip + io; io += E;
    int* csr    = ip + io; io += E;

    // ---- CSR build (by dst), shared by both layers; zero global atomics ----
    chunk_hist<<<NCH, 256, 0, stream>>>(dst, pcT, E, NB, NCC, NCH);
    coarse_total<<<NCC, 256, 0, stream>>>(pcT, totals, NCH);
    boffc_scan<<<1, 256, 0, stream>>>(totals, boffC, NCC);
    coarse_scan<<<NCC, 256, 0, stream>>>(pcT, boffC, co, NCH);
    coarse_partition<<<NCH, 256, 0, stream>>>(src, dst, co, csrA, E, NCC);
    node_sort<<<NCC, 256, 0, stream>>>(csrA, boffC, off, csr, N, NCC, E);

    // ---- layer 1 (FIN=128 -> 32) ----
    gemm_rows<128, 32, 8, 3><<<g1, 256, 0, stream>>>(
        x, W1, a1s, a1d, h1b, as1, ad1, bmax, N);
    rmax_w2prep<<<1, 256, 0, stream>>>(bmax, g1, gmax1, W2, a2s, a2d, w2s, w2d);
    gat_agg1<<<gn, 256, 0, stream>>>(
        csr, off, as1, ad1, h1b, b1, gmax1, w2s, w2d, h1a, as2, ad2, bmaxw, N);

    // ---- layer 2 (32 -> 64), gemm + alpha folded into aggregations ----
    reduce_max_kernel<<<1, 256, 0, stream>>>(bmaxw, gn * 4, gmax2);
    gat_agg2<<<gn, 256, 0, stream>>>(
        csr, off, as2, ad2, h1a, W2, b2, gmax2, out, N);
}

// Round 17
// 256.667 us; speedup vs baseline: 1.2344x; 1.2344x over previous
//
#include <hip/hip_runtime.h>
#include <cstdint>
#include <cmath>

#define NEG_SLOPE 0.2f
#define BSH 6                 // 64-node granularity for chunk_hist LDS hist
#define CSH 9                 // 512 nodes per coarse bucket
#define CBN 512               // 1 << CSH
#define RATIO 8               // CBN / 64
#define PCHUNK 8192           // edges per partition/hist chunk

__device__ __forceinline__ float leaky(float v) { return v > 0.f ? v : NEG_SLOPE * v; }
__device__ __forceinline__ float uf(unsigned u) { return __uint_as_float(u); }

// f32 -> bf16 round-to-nearest-even (finite inputs)
__device__ __forceinline__ unsigned short f2bf(float f) {
    unsigned u = __float_as_uint(f);
    unsigned r = ((u >> 16) & 1u) + 0x7fffu;
    return (unsigned short)((u + r) >> 16);
}
__device__ __forceinline__ float bflo(unsigned q) { return __uint_as_float(q << 16); }
__device__ __forceinline__ float bfhi(unsigned q) { return __uint_as_float(q & 0xffff0000u); }

// ---------------------------------------------------------------------------
// Skinny GEMM + attention-coefficient dots + per-block As-max (NO atomics):
//   H[n,:] = bf16(X[n,:] @ W) ;  As/Ad from full-precision acc;
//   bmax[blockIdx] = max As in block  (tiny reduce kernel folds to gmax).
// ---------------------------------------------------------------------------
template <int FIN, int FOUT, int CPR, int LCPR>
__global__ __launch_bounds__(256, 4) void gemm_rows(
    const float* __restrict__ X, const float* __restrict__ W,
    const float* __restrict__ a_src, const float* __restrict__ a_dst,
    unsigned short* __restrict__ H, float* __restrict__ As, float* __restrict__ Ad,
    float* __restrict__ bmax, int N)
{
    constexpr int ROWS = 256 / CPR;
    constexpr int XST = FIN + 4;              // padded row stride (floats)
    static_assert((1 << LCPR) == CPR && CPR * 4 == FOUT, "geometry");

    __shared__ float Ws[FIN * FOUT];
    __shared__ float Xs[ROWS * XST];
    __shared__ float wmax[4];

    const int tid = threadIdx.x;
    const int base = blockIdx.x * ROWS;

    for (int i = tid; i < FIN * FOUT / 4; i += 256)
        reinterpret_cast<float4*>(Ws)[i] = reinterpret_cast<const float4*>(W)[i];

    for (int i = tid; i < ROWS * FIN / 4; i += 256) {
        int row = i / (FIN / 4);
        int k4 = (i - row * (FIN / 4)) * 4;
        float4 v = make_float4(0.f, 0.f, 0.f, 0.f);
        if (base + row < N)
            v = *reinterpret_cast<const float4*>(&X[(size_t)(base + row) * FIN + k4]);
        *reinterpret_cast<float4*>(&Xs[row * XST + k4]) = v;
    }
    __syncthreads();

    const int colg = tid & (CPR - 1);
    const int row = tid >> LCPR;
    const int c0 = colg * 4;

    float4 acc = make_float4(0.f, 0.f, 0.f, 0.f);

#pragma unroll 2
    for (int k = 0; k < FIN; k += 4) {
        float4 xv = *reinterpret_cast<const float4*>(&Xs[row * XST + k]);
        float4 w0 = *reinterpret_cast<const float4*>(&Ws[(k + 0) * FOUT + c0]);
        float4 w1 = *reinterpret_cast<const float4*>(&Ws[(k + 1) * FOUT + c0]);
        float4 w2 = *reinterpret_cast<const float4*>(&Ws[(k + 2) * FOUT + c0]);
        float4 w3 = *reinterpret_cast<const float4*>(&Ws[(k + 3) * FOUT + c0]);
        acc.x = fmaf(xv.w, w3.x, fmaf(xv.z, w2.x, fmaf(xv.y, w1.x, fmaf(xv.x, w0.x, acc.x))));
        acc.y = fmaf(xv.w, w3.y, fmaf(xv.z, w2.y, fmaf(xv.y, w1.y, fmaf(xv.x, w0.y, acc.y))));
        acc.z = fmaf(xv.w, w3.z, fmaf(xv.z, w2.z, fmaf(xv.y, w1.z, fmaf(xv.x, w0.z, acc.z))));
        acc.w = fmaf(xv.w, w3.w, fmaf(xv.z, w2.w, fmaf(xv.y, w1.w, fmaf(xv.x, w0.w, acc.w))));
    }

    const int grow = base + row;
    if (grow < N) {
        ushort4 hv;
        hv.x = f2bf(acc.x); hv.y = f2bf(acc.y);
        hv.z = f2bf(acc.z); hv.w = f2bf(acc.w);
        *reinterpret_cast<ushort4*>(&H[(size_t)grow * FOUT + c0]) = hv;
    }

    float4 asv = *reinterpret_cast<const float4*>(&a_src[c0]);
    float4 adv = *reinterpret_cast<const float4*>(&a_dst[c0]);
    float ps = acc.x * asv.x + acc.y * asv.y + acc.z * asv.z + acc.w * asv.w;
    float pd = acc.x * adv.x + acc.y * adv.y + acc.z * adv.z + acc.w * adv.w;
#pragma unroll
    for (int ofs = 1; ofs < CPR; ofs <<= 1) {
        ps += __shfl_xor(ps, ofs);
        pd += __shfl_xor(pd, ofs);
    }
    if (colg == 0 && grow < N) { As[grow] = ps; Ad[grow] = pd; }

    // block max of As -> bmax[blockIdx] (no atomics)
    float pm = (grow < N) ? ps : -3.0e38f;
#pragma unroll
    for (int ofs = 1; ofs < 64; ofs <<= 1) pm = fmaxf(pm, __shfl_xor(pm, ofs));
    if ((tid & 63) == 0) wmax[tid >> 6] = pm;
    __syncthreads();
    if (tid == 0)
        bmax[blockIdx.x] = fmaxf(fmaxf(wmax[0], wmax[1]), fmaxf(wmax[2], wmax[3]));
}

// multi-block stage-1 max: partials[blockIdx] = max over grid-stride range
__global__ __launch_bounds__(256) void partial_max_kernel(
    const float* __restrict__ bmax, int nb, float* __restrict__ partials)
{
    __shared__ float sd[256];
    const int t = threadIdx.x;
    float m = -3.0e38f;
    for (int i = blockIdx.x * 256 + t; i < nb; i += gridDim.x * 256)
        m = fmaxf(m, bmax[i]);
    sd[t] = m; __syncthreads();
    for (int ofs = 128; ofs; ofs >>= 1) {
        if (t < ofs) sd[t] = fmaxf(sd[t], sd[t + ofs]);
        __syncthreads();
    }
    if (t == 0) partials[blockIdx.x] = sd[0];
}

// single block: gmax = max(bmax[0..nb))  (use only for small nb)
__global__ __launch_bounds__(256) void reduce_max_kernel(
    const float* __restrict__ bmax, int nb, float* __restrict__ gmax)
{
    __shared__ float sd[256];
    const int t = threadIdx.x;
    float m = -3.0e38f;
    for (int i = t; i < nb; i += 256) m = fmaxf(m, bmax[i]);
    sd[t] = m; __syncthreads();
    for (int ofs = 128; ofs; ofs >>= 1) {
        if (t < ofs) sd[t] = fmaxf(sd[t], sd[t + ofs]);
        __syncthreads();
    }
    if (t == 0) *gmax = sd[0];
}

// single block: gmax = max(bmax) ; also w2s = W2@a2s, w2d = W2@a2d (t<64).
__global__ __launch_bounds__(256) void rmax_w2prep(
    const float* __restrict__ bmax, int nb, float* __restrict__ gmax,
    const float* __restrict__ W2, const float* __restrict__ a2s,
    const float* __restrict__ a2d, float* __restrict__ w2s, float* __restrict__ w2d)
{
    __shared__ float sd[256];
    const int t = threadIdx.x;
    float m = -3.0e38f;
    for (int i = t; i < nb; i += 256) m = fmaxf(m, bmax[i]);
    sd[t] = m; __syncthreads();
    for (int ofs = 128; ofs; ofs >>= 1) {
        if (t < ofs) sd[t] = fmaxf(sd[t], sd[t + ofs]);
        __syncthreads();
    }
    if (t == 0) *gmax = sd[0];
    if (t < 64) {
        int i = t & 31;
        const float* a = (t < 32) ? a2s : a2d;
        float s = 0.f;
        for (int j = 0; j < 64; ++j) s = fmaf(W2[i * 64 + j], a[j], s);
        if (t < 32) w2s[i] = s; else w2d[i] = s;
    }
}

// ---------------------------------------------------------------------------
// CSR build (r13 form): 6 kernels, zero global atomics, no per-call memset.
// ---------------------------------------------------------------------------
__global__ __launch_bounds__(256) void chunk_hist(
    const int* __restrict__ dst, int* __restrict__ pcT,
    int E, int NB, int NCC, int NCH)
{
    __shared__ int hc[2048];
    const int t = threadIdx.x;
    for (int i = t; i < 2048; i += 256) hc[i] = 0;
    __syncthreads();
    const int base = blockIdx.x * PCHUNK;
    const int end = (base + PCHUNK < E) ? base + PCHUNK : E;
    for (int e = base + t; e < end; e += 256)
        atomicAdd(&hc[dst[e] >> BSH], 1);
    __syncthreads();
    if (t < NCC) {
        int f0 = t * RATIO;
        int s = 0;
#pragma unroll
        for (int j = 0; j < RATIO; ++j) {
            int fb = f0 + j;
            if (fb < NB) s += hc[fb];
        }
        pcT[(size_t)t * NCH + blockIdx.x] = s;
    }
}

__global__ __launch_bounds__(256) void coarse_total(
    const int* __restrict__ pcT, int* __restrict__ totals, int NCH)
{
    __shared__ int sd[256];
    const int t = threadIdx.x;
    int s = 0;
    for (int i = t; i < NCH; i += 256)
        s += pcT[(size_t)blockIdx.x * NCH + i];
    sd[t] = s; __syncthreads();
    for (int ofs = 128; ofs; ofs >>= 1) {
        if (t < ofs) sd[t] += sd[t + ofs];
        __syncthreads();
    }
    if (t == 0) totals[blockIdx.x] = sd[0];
}

__global__ __launch_bounds__(256) void boffc_scan(
    const int* __restrict__ totals, int* __restrict__ boffC, int NCC)
{
    __shared__ int sd[256];
    const int t = threadIdx.x;
    int v = (t < NCC) ? totals[t] : 0;
    sd[t] = v; __syncthreads();
    for (int ofs = 1; ofs < 256; ofs <<= 1) {
        int tmp = (t >= ofs) ? sd[t - ofs] : 0;
        __syncthreads();
        sd[t] += tmp;
        __syncthreads();
    }
    if (t < NCC) boffC[t] = sd[t] - v;
    if (t == 255) boffC[NCC] = sd[255];   // == E
}

__global__ __launch_bounds__(256) void coarse_scan(
    const int* __restrict__ pcT, const int* __restrict__ boffC,
    int* __restrict__ co, int NCH)
{
    __shared__ int sd[256];
    const int c = blockIdx.x;
    const int t = threadIdx.x;
    const int base = boffC[c];
    int carry = 0;
    for (int start = 0; start < NCH; start += 256) {
        int idx = start + t;
        int v = (idx < NCH) ? pcT[(size_t)c * NCH + idx] : 0;
        sd[t] = v; __syncthreads();
        for (int ofs = 1; ofs < 256; ofs <<= 1) {
            int tmp = (t >= ofs) ? sd[t - ofs] : 0;
            __syncthreads();
            sd[t] += tmp;
            __syncthreads();
        }
        int incl = sd[t];
        int total = sd[255];
        if (idx < NCH) co[(size_t)idx * 256 + c] = base + carry + incl - v;
        carry += total;
        __syncthreads();
    }
}

__global__ __launch_bounds__(256) void coarse_partition(
    const int* __restrict__ src, const int* __restrict__ dst,
    const int* __restrict__ co, int* __restrict__ csrA, int E, int NCC)
{
    __shared__ int lcur[256], gpos[256];
    const int t = threadIdx.x;
    lcur[t] = 0;
    if (t < NCC) gpos[t] = co[(size_t)blockIdx.x * 256 + t];
    __syncthreads();
    const int base = blockIdx.x * PCHUNK;
    int bb[32], pp[32];
#pragma unroll
    for (int i = 0; i < 32; ++i) {
        int e = base + i * 256 + t;
        bb[i] = -1;
        if (e < E) {
            int sv = src[e], dv = dst[e];
            bb[i] = dv >> CSH;
            pp[i] = (sv << CSH) | (dv & (CBN - 1));
        }
    }
#pragma unroll
    for (int i = 0; i < 32; ++i) {
        if (bb[i] >= 0) {
            int b = bb[i];
            csrA[gpos[b] + atomicAdd(&lcur[b], 1)] = pp[i];
        }
    }
}

__global__ __launch_bounds__(256) void node_sort(
    const int* __restrict__ csrA, const int* __restrict__ boffC,
    int* __restrict__ off, int* __restrict__ csr, int N, int NCC, int E)
{
    __shared__ int cnt[CBN];
    __shared__ int pref[CBN];
    __shared__ int sd[256];
    const int c = blockIdx.x;
    const int t = threadIdx.x;
    const int p0 = boffC[c];
    const int p1 = boffC[c + 1];
    const int n0 = c << CSH;

    for (int i = t; i < CBN; i += 256) cnt[i] = 0;
    __syncthreads();
    for (int i = p0 + t; i < p1; i += 256)
        atomicAdd(&cnt[csrA[i] & (CBN - 1)], 1);
    __syncthreads();
    int a0 = cnt[2 * t], a1 = cnt[2 * t + 1];
    int pairsum = a0 + a1;
    sd[t] = pairsum; __syncthreads();
    for (int ofs = 1; ofs < 256; ofs <<= 1) {
        int tmp = (t >= ofs) ? sd[t - ofs] : 0;
        __syncthreads();
        sd[t] += tmp;
        __syncthreads();
    }
    int run = sd[t] - pairsum;
    pref[2 * t] = run;
    pref[2 * t + 1] = run + a0;
    int n = n0 + 2 * t;
    if (n < N) off[n] = p0 + run;
    if (n + 1 < N) off[n + 1] = p0 + run + a0;
    if (c == NCC - 1 && t == 0) off[N] = E;
    __syncthreads();
    for (int i = t; i < CBN; i += 256) cnt[i] = 0;   // reuse as cursors
    __syncthreads();
    for (int i = p0 + t; i < p1; i += 256) {
        int v = csrA[i];
        int ln = v & (CBN - 1);
        int p = atomicAdd(&cnt[ln], 1);
        csr[p0 + pref[ln] + p] = v >> CSH;
    }
}

// ---------------------------------------------------------------------------
// Layer-1 aggregation + fused layer-2 alpha dots:
//   h1a = bf16(relu(agg/den + b1))  [gather table for agg2]
//   as2/ad2 from the exact f32 values (pre-rounding) via w2s/w2d
//   per-wave as2 maxima -> bmaxw (dead waves write -3e38).
// ---------------------------------------------------------------------------
__global__ __launch_bounds__(256) void gat_agg1(
    const int* __restrict__ csr, const int* __restrict__ off,
    const float* __restrict__ As, const float* __restrict__ Ad,
    const unsigned short* __restrict__ Hb, const float* __restrict__ bias,
    const float* __restrict__ gmax, const float* __restrict__ w2s,
    const float* __restrict__ w2d, unsigned short* __restrict__ Out,
    float* __restrict__ As2, float* __restrict__ Ad2,
    float* __restrict__ bmaxw, int N)
{
    constexpr int LPR = 8;            // lanes per row (4 bf16 per lane)
    constexpr int EPI = 8;            // edges in flight
    constexpr unsigned RB = 64;       // row bytes

    __shared__ uint2 pr[4][64];
    const int wave = threadIdx.x >> 6;
    const int lane = threadIdx.x & 63;
    const int n = blockIdx.x * 4 + wave;
    if (n >= N) {
        if (lane == 0) bmaxw[blockIdx.x * 4 + wave] = -3.0e38f;
        return;
    }

    const int o0 = off[n];
    const int deg = off[n + 1] - o0;
    const float adn = Ad[n];
    const float eself = leaky(As[n] + adn);
    const float m = leaky(*gmax + adn);

    uint2* myp = pr[wave];
    const char* Hc = (const char*)Hb;
    const int subg = lane / LPR;
    const unsigned f8 = (unsigned)(lane & (LPR - 1)) * 8u;

    float4 acc = make_float4(0.f, 0.f, 0.f, 0.f);
    float denp = 0.f;

    for (int c = 0; c < deg; c += 64) {
        int i = c + lane;
        float w = 0.f; unsigned sb = 0;
        if (i < deg) {
            int s = csr[o0 + i];
            w = __expf(leaky(As[s] + adn) - m);
            sb = (unsigned)s * RB;
            denp += w;
        }
        myp[lane] = make_uint2(sb, __float_as_uint(w));
        int lim = (deg - c < 64) ? deg - c : 64;
        int j = subg;
        for (; j + 3 * EPI < lim; j += 4 * EPI) {
            uint2 p0 = myp[j], p1 = myp[j + EPI], p2 = myp[j + 2 * EPI], p3 = myp[j + 3 * EPI];
            uint2 q0 = *(const uint2*)(Hc + p0.x + f8);
            uint2 q1 = *(const uint2*)(Hc + p1.x + f8);
            uint2 q2 = *(const uint2*)(Hc + p2.x + f8);
            uint2 q3 = *(const uint2*)(Hc + p3.x + f8);
            float w0 = uf(p0.y), w1 = uf(p1.y), w2 = uf(p2.y), w3 = uf(p3.y);
            acc.x = fmaf(w0, bflo(q0.x), acc.x); acc.y = fmaf(w0, bfhi(q0.x), acc.y);
            acc.z = fmaf(w0, bflo(q0.y), acc.z); acc.w = fmaf(w0, bfhi(q0.y), acc.w);
            acc.x = fmaf(w1, bflo(q1.x), acc.x); acc.y = fmaf(w1, bfhi(q1.x), acc.y);
            acc.z = fmaf(w1, bflo(q1.y), acc.z); acc.w = fmaf(w1, bfhi(q1.y), acc.w);
            acc.x = fmaf(w2, bflo(q2.x), acc.x); acc.y = fmaf(w2, bfhi(q2.x), acc.y);
            acc.z = fmaf(w2, bflo(q2.y), acc.z); acc.w = fmaf(w2, bfhi(q2.y), acc.w);
            acc.x = fmaf(w3, bflo(q3.x), acc.x); acc.y = fmaf(w3, bfhi(q3.x), acc.y);
            acc.z = fmaf(w3, bflo(q3.y), acc.z); acc.w = fmaf(w3, bfhi(q3.y), acc.w);
        }
        for (; j < lim; j += EPI) {
            uint2 p = myp[j];
            uint2 q = *(const uint2*)(Hc + p.x + f8);
            float w0 = uf(p.y);
            acc.x = fmaf(w0, bflo(q.x), acc.x); acc.y = fmaf(w0, bfhi(q.x), acc.y);
            acc.z = fmaf(w0, bflo(q.y), acc.z); acc.w = fmaf(w0, bfhi(q.y), acc.w);
        }
    }

#pragma unroll
    for (int ofs = 32; ofs >= LPR; ofs >>= 1) {
        acc.x += __shfl_xor(acc.x, ofs);
        acc.y += __shfl_xor(acc.y, ofs);
        acc.z += __shfl_xor(acc.z, ofs);
        acc.w += __shfl_xor(acc.w, ofs);
    }
#pragma unroll
    for (int ofs = 1; ofs < 64; ofs <<= 1) denp += __shfl_xor(denp, ofs);

    float wsf = __expf(eself - m);
    uint2 qs = *(const uint2*)(Hc + (size_t)n * RB + f8);
    acc.x = fmaf(wsf, bflo(qs.x), acc.x); acc.y = fmaf(wsf, bfhi(qs.x), acc.y);
    acc.z = fmaf(wsf, bflo(qs.y), acc.z); acc.w = fmaf(wsf, bfhi(qs.y), acc.w);
    float den = denp + wsf;

    // every lane now holds the reduced acc for its 4-feature slot
    const int fi = (lane & (LPR - 1)) * 4;
    float4 bv = *reinterpret_cast<const float4*>(&bias[fi]);
    float vx = fmaxf(acc.x / den + bv.x, 0.f);
    float vy = fmaxf(acc.y / den + bv.y, 0.f);
    float vz = fmaxf(acc.z / den + bv.z, 0.f);
    float vw = fmaxf(acc.w / den + bv.w, 0.f);

    if (subg == 0) {
        ushort4 hv;
        hv.x = f2bf(vx); hv.y = f2bf(vy); hv.z = f2bf(vz); hv.w = f2bf(vw);
        *reinterpret_cast<ushort4*>(&Out[(size_t)n * 32 + fi]) = hv;
    }

    // fused alpha2 from exact f32 values (bit-identical to separate f32 pass)
    float ps = vx * w2s[fi] + vy * w2s[fi + 1] + vz * w2s[fi + 2] + vw * w2s[fi + 3];
    float pd = vx * w2d[fi] + vy * w2d[fi + 1] + vz * w2d[fi + 2] + vw * w2d[fi + 3];
#pragma unroll
    for (int ofs = 1; ofs < LPR; ofs <<= 1) {
        ps += __shfl_xor(ps, ofs);
        pd += __shfl_xor(pd, ofs);
    }
    if (lane == 0) {
        As2[n] = ps; Ad2[n] = pd;
        bmaxw[blockIdx.x * 4 + wave] = ps;
    }
}

// ---------------------------------------------------------------------------
// Layer-2 aggregation, fused @W2 (W2 read direct from global; L1-hot):
// gathers 64B bf16 h1a rows, agg32 = sum(alpha*h1a[s]) + self,
// out = agg32@W2/den + b2. No barriers.
// ---------------------------------------------------------------------------
__global__ __launch_bounds__(256) void gat_agg2(
    const int* __restrict__ csr, const int* __restrict__ off,
    const float* __restrict__ As, const float* __restrict__ Ad,
    const unsigned short* __restrict__ Hb, const float* __restrict__ W2,
    const float* __restrict__ b2, const float* __restrict__ gmax,
    float* __restrict__ Out, int N)
{
    constexpr int LPR = 8;
    constexpr int EPI = 8;
    constexpr unsigned RB = 64;

    __shared__ uint2 pr[4][64];
    __shared__ float aggv[4][32];

    const int tid = threadIdx.x;
    const int wave = tid >> 6;
    const int lane = tid & 63;
    const int n = blockIdx.x * 4 + wave;
    if (n >= N) return;

    const int o0 = off[n];
    const int deg = off[n + 1] - o0;
    const float adn = Ad[n];
    const float eself = leaky(As[n] + adn);
    const float m = leaky(*gmax + adn);

    uint2* myp = pr[wave];
    const char* Hc = (const char*)Hb;
    const int subg = lane / LPR;
    const unsigned f8 = (unsigned)(lane & (LPR - 1)) * 8u;

    float4 acc = make_float4(0.f, 0.f, 0.f, 0.f);
    float denp = 0.f;

    for (int c = 0; c < deg; c += 64) {
        int i = c + lane;
        float w = 0.f; unsigned sb = 0;
        if (i < deg) {
            int s = csr[o0 + i];
            w = __expf(leaky(As[s] + adn) - m);
            sb = (unsigned)s * RB;
            denp += w;
        }
        myp[lane] = make_uint2(sb, __float_as_uint(w));
        int lim = (deg - c < 64) ? deg - c : 64;
        int j = subg;
        for (; j + 3 * EPI < lim; j += 4 * EPI) {
            uint2 p0 = myp[j], p1 = myp[j + EPI], p2 = myp[j + 2 * EPI], p3 = myp[j + 3 * EPI];
            uint2 q0 = *(const uint2*)(Hc + p0.x + f8);
            uint2 q1 = *(const uint2*)(Hc + p1.x + f8);
            uint2 q2 = *(const uint2*)(Hc + p2.x + f8);
            uint2 q3 = *(const uint2*)(Hc + p3.x + f8);
            float w0 = uf(p0.y), w1 = uf(p1.y), w2 = uf(p2.y), w3 = uf(p3.y);
            acc.x = fmaf(w0, bflo(q0.x), acc.x); acc.y = fmaf(w0, bfhi(q0.x), acc.y);
            acc.z = fmaf(w0, bflo(q0.y), acc.z); acc.w = fmaf(w0, bfhi(q0.y), acc.w);
            acc.x = fmaf(w1, bflo(q1.x), acc.x); acc.y = fmaf(w1, bfhi(q1.x), acc.y);
            acc.z = fmaf(w1, bflo(q1.y), acc.z); acc.w = fmaf(w1, bfhi(q1.y), acc.w);
            acc.x = fmaf(w2, bflo(q2.x), acc.x); acc.y = fmaf(w2, bfhi(q2.x), acc.y);
            acc.z = fmaf(w2, bflo(q2.y), acc.z); acc.w = fmaf(w2, bfhi(q2.y), acc.w);
            acc.x = fmaf(w3, bflo(q3.x), acc.x); acc.y = fmaf(w3, bfhi(q3.x), acc.y);
            acc.z = fmaf(w3, bflo(q3.y), acc.z); acc.w = fmaf(w3, bfhi(q3.y), acc.w);
        }
        for (; j < lim; j += EPI) {
            uint2 p = myp[j];
            uint2 q = *(const uint2*)(Hc + p.x + f8);
            float w0 = uf(p.y);
            acc.x = fmaf(w0, bflo(q.x), acc.x); acc.y = fmaf(w0, bfhi(q.x), acc.y);
            acc.z = fmaf(w0, bflo(q.y), acc.z); acc.w = fmaf(w0, bfhi(q.y), acc.w);
        }
    }

#pragma unroll
    for (int ofs = 32; ofs >= LPR; ofs >>= 1) {
        acc.x += __shfl_xor(acc.x, ofs);
        acc.y += __shfl_xor(acc.y, ofs);
        acc.z += __shfl_xor(acc.z, ofs);
        acc.w += __shfl_xor(acc.w, ofs);
    }
#pragma unroll
    for (int ofs = 1; ofs < 64; ofs <<= 1) denp += __shfl_xor(denp, ofs);

    float wsf = __expf(eself - m);
    uint2 qs = *(const uint2*)(Hc + (size_t)n * RB + f8);
    acc.x = fmaf(wsf, bflo(qs.x), acc.x); acc.y = fmaf(wsf, bfhi(qs.x), acc.y);
    acc.z = fmaf(wsf, bflo(qs.y), acc.z); acc.w = fmaf(wsf, bfhi(qs.y), acc.w);
    float den = denp + wsf;

    if (subg == 0)
        *reinterpret_cast<float4*>(&aggv[wave][(lane & (LPR - 1)) * 4]) = acc;
    // same-wave LDS write->read is ordered; compiler inserts lgkmcnt wait

    float s = 0.f;
#pragma unroll
    for (int k = 0; k < 32; ++k)
        s = fmaf(aggv[wave][k], W2[k * 64 + lane], s);
    Out[(size_t)n * 64 + lane] = s / den + b2[lane];
}

// ---------------------------------------------------------------------------
extern "C" void kernel_launch(void* const* d_in, const int* in_sizes, int n_in,
                              void* d_out, int out_size, void* d_ws, size_t ws_size,
                              hipStream_t stream)
{
    const float* x   = (const float*)d_in[0];
    const int*   ei  = (const int*)d_in[1];   // [2, E] int32
    const float* W1  = (const float*)d_in[2];
    const float* a1s = (const float*)d_in[3];
    const float* a1d = (const float*)d_in[4];
    const float* b1  = (const float*)d_in[5];
    const float* W2  = (const float*)d_in[6];
    const float* a2s = (const float*)d_in[7];
    const float* a2d = (const float*)d_in[8];
    const float* b2  = (const float*)d_in[9];

    const int N = in_sizes[0] / 128;
    const int E = in_sizes[1] / 2;
    const int NB = (N + 63) >> BSH;                 // 64-node fine granularity
    const int NCC = (N + CBN - 1) >> CSH;           // coarse buckets (<=256)
    const int NCH = (E + PCHUNK - 1) / PCHUNK;
    const int* src = ei;
    const int* dst = ei + E;
    float* out = (float*)d_out;

    const int g1 = (N + 31) / 32;   // layer-1 gemm grid
    const int gn = (N + 3) / 4;     // aggregation grid
    const int PB = 128;             // stage-1 max-reduce blocks

    // ---- workspace layout ----
    float* ws = (float*)d_ws;
    size_t o = 0;
    unsigned short* h1b = (unsigned short*)(ws + o); o += (size_t)N * 16;  // N*32 bf16
    unsigned short* h1a = (unsigned short*)(ws + o); o += (size_t)N * 16;  // N*32 bf16
    float* as1 = ws + o; o += N;
    float* ad1 = ws + o; o += N;
    float* as2 = ws + o; o += N;
    float* ad2 = ws + o; o += N;
    float* bmax = ws + o; o += (size_t)g1;
    float* bmaxw = ws + o; o += (size_t)gn * 4;
    float* partials = ws + o; o += PB;
    float* gmax1 = ws + o; o += 1;
    float* gmax2 = ws + o; o += 1;
    float* w2s = ws + o; o += 32;
    float* w2d = ws + o; o += 32;
    int* ip = (int*)(ws + o);
    size_t io = 0;
    int* pcT    = ip + io; io += (size_t)NCC * NCH;
    int* totals = ip + io; io += NCC;
    int* boffC  = ip + io; io += (NCC + 1);
    int* co     = ip + io; io += (size_t)NCH * 256;
    int* off    = ip + io; io += (N + 1);
    int* csrA   = ip + io; io += E;
    int* csr    = ip + io; io += E;

    // ---- CSR build (by dst), shared by both layers; zero global atomics ----
    chunk_hist<<<NCH, 256, 0, stream>>>(dst, pcT, E, NB, NCC, NCH);
    coarse_total<<<NCC, 256, 0, stream>>>(pcT, totals, NCH);
    boffc_scan<<<1, 256, 0, stream>>>(totals, boffC, NCC);
    coarse_scan<<<NCC, 256, 0, stream>>>(pcT, boffC, co, NCH);
    coarse_partition<<<NCH, 256, 0, stream>>>(src, dst, co, csrA, E, NCC);
    node_sort<<<NCC, 256, 0, stream>>>(csrA, boffC, off, csr, N, NCC, E);

    // ---- layer 1 (FIN=128 -> 32) ----
    gemm_rows<128, 32, 8, 3><<<g1, 256, 0, stream>>>(
        x, W1, a1s, a1d, h1b, as1, ad1, bmax, N);
    rmax_w2prep<<<1, 256, 0, stream>>>(bmax, g1, gmax1, W2, a2s, a2d, w2s, w2d);
    gat_agg1<<<gn, 256, 0, stream>>>(
        csr, off, as1, ad1, h1b, b1, gmax1, w2s, w2d, h1a, as2, ad2, bmaxw, N);

    // ---- layer 2 (32 -> 64), gemm + alpha folded into aggregations ----
    partial_max_kernel<<<PB, 256, 0, stream>>>(bmaxw, gn * 4, partials);
    reduce_max_kernel<<<1, 256, 0, stream>>>(partials, PB, gmax2);
    gat_agg2<<<gn, 256, 0, stream>>>(
        csr, off, as2, ad2, h1a, W2, b2, gmax2, out, N);
}